// Round 1
// 187.734 us; speedup vs baseline: 1.1835x; 1.1835x over previous
//
#include <hip/hip_runtime.h>
#include <hip/hip_fp16.h>
#include <math.h>

#define N_NODES 50000
#define N_EDGES 1600000
#define NB 2000      // dst buckets; NB*NPB == N_NODES
#define NPB 25       // dst nodes per bucket (dstLocal in 5 bits)
#define NCH 100      // edge chunks
#define EPC 16000    // edges per chunk
#define CAPC 32      // slots per (bucket,chunk) cell: Poisson(8) + ~8 sigma
#define CAP_LDS 1280 // max edges per bucket (mean 800, +17 sigma)
#define SPLIT 8      // place: blocks per chunk (bucket-range partition)
#define BPS (NB / SPLIT)                        // 250
#define PLACE_BLOCKS (NCH * SPLIT)              // 800
#define PROJ_BLOCKS ((N_NODES + 31) / 32)       // 1563

typedef _Float16 f16x8 __attribute__((ext_vector_type(8)));
typedef float f32x4 __attribute__((ext_vector_type(4)));

// ---- workspace layout (bytes) ----
// h16q   : 0           12,800,000  __half QUARTER-MAJOR [4][N_NODES][32]
// s_src  : 12,800,000     200,000  float[N]
// s_dst  : 13,000,000     200,000  float[N]
// cnt    : 13,200,000     800,000  int[NCH*NB] (chunk-major)
// gep    : 14,000,000  25,600,000  u32[NB*3200]; cells, then overwritten
//                                  in-place by k_sort with sorted (src<<16)|a16
// rp_g   : 39,600,000     256,000  int[NB*32] per-bucket rowptr (26 used)
// w16q   : 39,856,000      32,768  __half[16384] W in MFMA B-fragment order
// waSD   : 39,888,768       1,024  float[256]: waS[128] then waD[128]
// cst    : 39,889,792           8  float[2]: bS, bD
// total ~39.89 MB

// Tiny prep kernel: W -> f16 B-fragment layout + folded attention vectors.
//   waS = W @ attn_w[:128], waD = W @ attn_w[128:], bS = b.aS, bD = b.aD
// (s_src = h@aS = x_masked@waS + bS by linearity -> dots decouple from GEMM)
__global__ __launch_bounds__(256) void k_prep(const float* __restrict__ W,
                                              const float* __restrict__ b,
                                              const float* __restrict__ attn_w,
                                              __half* __restrict__ w16q,
                                              float* __restrict__ waSD,
                                              float* __restrict__ cst) {
    const int blk = blockIdx.x, t = threadIdx.x;
    if (blk < 8) {
        // waS/waD: row k = blk*16 + (t>>4), 16 lanes per row, shfl-reduce
        const int k = blk * 16 + (t >> 4), sub = t & 15;
        const float4* W4 = (const float4*)W;
        float4 w0 = W4[k * 32 + sub * 2];
        float4 w1 = W4[k * 32 + sub * 2 + 1];
        const int j0 = sub * 8;
        float pS = w0.x * attn_w[j0]     + w0.y * attn_w[j0 + 1]
                 + w0.z * attn_w[j0 + 2] + w0.w * attn_w[j0 + 3]
                 + w1.x * attn_w[j0 + 4] + w1.y * attn_w[j0 + 5]
                 + w1.z * attn_w[j0 + 6] + w1.w * attn_w[j0 + 7];
        float pD = w0.x * attn_w[128 + j0]     + w0.y * attn_w[128 + j0 + 1]
                 + w0.z * attn_w[128 + j0 + 2] + w0.w * attn_w[128 + j0 + 3]
                 + w1.x * attn_w[128 + j0 + 4] + w1.y * attn_w[128 + j0 + 5]
                 + w1.z * attn_w[128 + j0 + 6] + w1.w * attn_w[128 + j0 + 7];
        pS += __shfl_down(pS, 8); pS += __shfl_down(pS, 4);
        pS += __shfl_down(pS, 2); pS += __shfl_down(pS, 1);
        pD += __shfl_down(pD, 8); pD += __shfl_down(pD, 4);
        pD += __shfl_down(pD, 2); pD += __shfl_down(pD, 1);
        if (sub == 0) { waSD[k] = pS; waSD[128 + k] = pD; }
    } else if (blk < 40) {
        // w16q element e = ((ct*4+kb)*64 + l)*8 + j  holds
        //   (half) W[kb*32 + (l>>4)*8 + j][ct*16 + (l&15)]
        for (int e = (blk - 8) * 256 + t; e < 16384; e += 8192) {
            int j = e & 7, l = (e >> 3) & 63, kb = (e >> 9) & 3, ct = e >> 11;
            int k = kb * 32 + (l >> 4) * 8 + j;
            int c = ct * 16 + (l & 15);
            w16q[e] = __float2half(W[k * 128 + c]);
        }
    } else if (t < 64) {
        float vS = b[t] * attn_w[t]       + b[t + 64] * attn_w[t + 64];
        float vD = b[t] * attn_w[128 + t] + b[t + 64] * attn_w[192 + t];
        for (int off = 32; off; off >>= 1) {
            vS += __shfl_down(vS, off);
            vD += __shfl_down(vD, off);
        }
        if (t == 0) { cst[0] = vS; cst[1] = vD; }
    }
}

// Fused block-specialized kernel. Union LDS = 33 KB -> 4 blocks/CU for BOTH
// paths (round-9's 66 KB union capped everything at 2/CU - the fix).
//   blocks [0, 800):    edge binning, chunk c = blk>>3, quartile sp = blk&7
//   blocks [800, 2363): MFMA projection + attention dots (proj LDS 9.7 KB)
__global__ __launch_bounds__(512) void k_fusedA(const float* __restrict__ feat,
                                                const float* __restrict__ b,
                                                const float* __restrict__ mask,
                                                const int* __restrict__ src,
                                                const int* __restrict__ dst,
                                                __half* __restrict__ h16q,
                                                float* __restrict__ s_src,
                                                float* __restrict__ s_dst,
                                                int* __restrict__ cnt,
                                                unsigned* __restrict__ gep,
                                                const __half* __restrict__ w16q,
                                                const float* __restrict__ waSD,
                                                const float* __restrict__ cst) {
    __shared__ __align__(16) char smem[33024];  // place 33 KB / proj 9.7 KB
    const int blk = blockIdx.x;
    const int t = threadIdx.x;

    if (blk < PLACE_BLOCKS) {
        // ---------------- place path (unchanged) ----------------
        int* cur = (int*)smem;                        // [BPS] 1000 B
        unsigned* lcell = (unsigned*)(smem + 1024);   // [BPS*CAPC] 32000 B
        const int c = blk >> 3, sp = blk & 7;
        const int b0 = sp * BPS;
        for (int i = t; i < BPS; i += 512) cur[i] = 0;
        __syncthreads();
        const int q0 = c * (EPC / 4);
        for (int q = t; q < EPC / 4; q += 512) {
            int4 s4 = ((const int4*)src)[q0 + q];
            int4 d4 = ((const int4*)dst)[q0 + q];
            int ss[4] = {s4.x, s4.y, s4.z, s4.w};
            int dd[4] = {d4.x, d4.y, d4.z, d4.w};
#pragma unroll
            for (int k = 0; k < 4; k++) {
                int d = dd[k];
                int bkt = d / NPB;           // magic-mul
                if (bkt >= b0 && bkt < b0 + BPS) {
                    int dl = d - bkt * NPB;
                    int lb = bkt - b0;
                    int r = atomicAdd(&cur[lb], 1);
                    if (r < CAPC)
                        lcell[lb * CAPC + r] = ((unsigned)ss[k] << 5) | (unsigned)dl;
                }
            }
        }
        __syncthreads();
        // coalesced cell write-out: 8 uint4 per cell (128 B, one full line)
        const uint4* lc4 = (const uint4*)lcell;
        uint4* gp4 = (uint4*)gep;
        for (int idx = t; idx < BPS * (CAPC / 4); idx += 512) {
            int i = idx >> 3, q = idx & 7;
            gp4[((size_t)(b0 + i) * NCH + c) * 8 + q] = lc4[idx];
        }
        for (int i = t; i < BPS; i += 512) cnt[c * NB + b0 + i] = min(cur[i], CAPC);
    } else {
        // ---------------- MFMA projection + dots path ----------------
        // LDS: a16[32][128] halves XOR-swizzled (byte ^= (row&7)<<4) : 8192 B
        //      sAW @8192 (512 B), sAD @8704 (512 B), sig @9216 (512 B)
        float* sAW = (float*)(smem + 8192);
        float* sAD = (float*)(smem + 8704);
        float* sig = (float*)(smem + 9216);
        const int bb = blk - PLACE_BLOCKS;
        const int row0 = bb * 32;
        if (t < 128) {
            sig[t] = 1.f / (1.f + expf(-mask[t]));
            sAW[t] = waSD[t];
            sAD[t] = waSD[128 + t];
        }
        __syncthreads();
        // feat tile: float4 load -> mask -> f16 -> swizzled LDS (8 B stores)
        for (int idx = t; idx < 32 * 32; idx += 512) {
            int r = idx >> 5, c4 = idx & 31;
            int grow = row0 + r;
            float4 f;
            if (grow < N_NODES) f = ((const float4*)feat)[grow * 32 + c4];
            else f = make_float4(0.f, 0.f, 0.f, 0.f);
            int c = c4 * 4;
            ushort4 pk;
            pk.x = __half_as_ushort(__float2half(f.x * sig[c]));
            pk.y = __half_as_ushort(__float2half(f.y * sig[c + 1]));
            pk.z = __half_as_ushort(__float2half(f.z * sig[c + 2]));
            pk.w = __half_as_ushort(__float2half(f.w * sig[c + 3]));
            int byte = (r * 256 + c4 * 8) ^ ((r & 7) << 4);
            *(ushort4*)(smem + byte) = pk;
        }
        __syncthreads();
        // wave wv owns col-tile ct=wv (cols wv*16..+15); row-tiles m=0,1.
        // A frag: lane l holds A[l&15][(l>>4)*8 + j]; B frag from w16q.
        const int wv = t >> 6, l = t & 63;
        const int lr = l & 15, lk = l >> 4;
        const f16x8* wq = (const f16x8*)w16q;
        f32x4 acc0 = {0.f, 0.f, 0.f, 0.f};
        f32x4 acc1 = {0.f, 0.f, 0.f, 0.f};
#pragma unroll
        for (int kb = 0; kb < 4; kb++) {
            f16x8 Bf = wq[(wv * 4 + kb) * 64 + l];
            int co = kb * 64 + lk * 16;                     // k-slice byte off
            f16x8 A0 = *(const f16x8*)(smem + ((lr * 256 + co) ^ ((lr & 7) << 4)));
            f16x8 A1 = *(const f16x8*)(smem + (((16 + lr) * 256 + co) ^ ((lr & 7) << 4)));
            acc0 = __builtin_amdgcn_mfma_f32_16x16x32_f16(A0, Bf, acc0, 0, 0, 0);
            acc1 = __builtin_amdgcn_mfma_f32_16x16x32_f16(A1, Bf, acc1, 0, 0, 0);
        }
        // dots: s_src/s_dst from a16 directly (folded waS/waD) - independent
        // of the MFMA results, no extra barrier.
        {
            const int r2 = t >> 4, sub = t & 15;
            f16x8 xv = *(const f16x8*)(smem + ((r2 * 256 + sub * 16) ^ ((r2 & 7) << 4)));
            float ss = 0.f, sd = 0.f;
#pragma unroll
            for (int q = 0; q < 8; q++) {
                float v = (float)xv[q];
                int jj = sub * 8 + q;
                ss = fmaf(v, sAW[jj], ss);
                sd = fmaf(v, sAD[jj], sd);
            }
            ss += __shfl_down(ss, 8); ss += __shfl_down(ss, 4);
            ss += __shfl_down(ss, 2); ss += __shfl_down(ss, 1);
            sd += __shfl_down(sd, 8); sd += __shfl_down(sd, 4);
            sd += __shfl_down(sd, 2); sd += __shfl_down(sd, 1);
            int grow = row0 + r2;
            if (sub == 0 && grow < N_NODES) {
                s_src[grow] = ss + cst[0];
                s_dst[grow] = sd + cst[1];
            }
        }
        // epilogue: C frag col = lr, row = lk*4 + reg; add bias, store fp16
        const float bj = b[wv * 16 + lr];
        __half* hp = h16q + (size_t)(wv >> 1) * (N_NODES * 32) + ((wv & 1) * 16 + lr);
#pragma unroll
        for (int reg = 0; reg < 4; reg++) {
            int n0 = row0 + lk * 4 + reg;
            if (n0 < N_NODES) hp[(size_t)n0 * 32] = __float2half(acc0[reg] + bj);
            int n1 = n0 + 16;
            if (n1 < N_NODES) hp[(size_t)n1 * 32] = __float2half(acc1[reg] + bj);
        }
    }
}

// per-bucket: DENSE coalesced cell read -> LDS counting sort by dstLocal ->
// exp weights -> per-node denom (LDS atomics) -> pre-normalized a=w/denom
// packed (src<<16)|fp16(a), written in place over own gep region + rowptr.
__global__ __launch_bounds__(256) void k_sort(const float* __restrict__ s_src,
                                              const float* __restrict__ s_dst,
                                              const float* __restrict__ attn_b,
                                              const int* __restrict__ cnt,
                                              unsigned* gep,
                                              int* __restrict__ rp_g) {
    __shared__ unsigned raw[CAP_LDS];
    __shared__ unsigned srt[CAP_LDS];   // (src<<16)|dl during pass A
    __shared__ float wbuf[CAP_LDS];
    __shared__ int ccnt[NCH];
    __shared__ int coff[NCH];
    __shared__ int hist[NPB];
    __shared__ int rp[NPB + 1];
    __shared__ int curn[NPB];
    __shared__ float sdl[NPB];
    __shared__ float dsum[NPB];
    __shared__ float dinv[NPB];
    __shared__ int totsh;
    const int bkt = blockIdx.x;
    const int t = threadIdx.x;
    if (t < NCH) ccnt[t] = cnt[t * NB + bkt];
    if (t < NPB) { hist[t] = 0; dsum[t] = 0.f; sdl[t] = s_dst[bkt * NPB + t]; }
    __syncthreads();
    if (t < 64) {   // exclusive scan of 100 cell counts (wave 0)
        int i0 = 2 * t, i1 = 2 * t + 1;
        int a0 = (i0 < NCH) ? ccnt[i0] : 0;
        int a1 = (i1 < NCH) ? ccnt[i1] : 0;
        int s = a0 + a1, incl = s;
#pragma unroll
        for (int off = 1; off < 64; off <<= 1) {
            int v = __shfl_up(incl, off);
            if (t >= off) incl += v;
        }
        int excl = incl - s;
        if (i0 < NCH) coff[i0] = excl;
        if (i1 < NCH) coff[i1] = excl + a0;
        if (t == 63) totsh = incl;
    }
    __syncthreads();
    int total = totsh;
    if (total > CAP_LDS) total = CAP_LDS;
    unsigned* gb = gep + (size_t)bkt * (NCH * CAPC);
    // dense cell read: full-line coalesced; predicate gates only the LDS write
    for (int i = t; i < NCH * CAPC; i += 256) {
        unsigned e = gb[i];
        int cell = i >> 5, slot = i & 31;
        if (slot < ccnt[cell]) {
            int pos = coff[cell] + slot;
            if (pos < CAP_LDS) {
                raw[pos] = e;
                atomicAdd(&hist[e & 31], 1);
            }
        }
    }
    __syncthreads();
    if (t == 0) {
        int run = 0;
        for (int j = 0; j < NPB; j++) { rp[j] = run; curn[j] = run; run += hist[j]; }
        rp[NPB] = run;
    }
    __syncthreads();
    const float ab = attn_b[0];
    for (int i = t; i < total; i += 256) {   // pass A: exp + denom accumulate
        unsigned e = raw[i];
        int dl = e & 31;
        int s = (int)(e >> 5);
        float sc = s_src[s] + sdl[dl] + ab;
        sc = sc >= 0.f ? sc : 0.01f * sc;   // leaky_relu; |sc| small, exp safe
        float w = expf(sc);
        int pos = atomicAdd(&curn[dl], 1);
        srt[pos] = ((unsigned)s << 16) | (unsigned)dl;
        wbuf[pos] = w;
        atomicAdd(&dsum[dl], w);
    }
    __syncthreads();
    if (t < NPB) dinv[t] = dsum[t] > 0.f ? 1.f / dsum[t] : 0.f;
    __syncthreads();
    for (int i = t; i < total; i += 256) {   // pass B: normalize + pack
        unsigned e = srt[i];
        float a = wbuf[i] * dinv[e & 31];
        gb[i] = (e & 0xFFFF0000u) | (unsigned)__half_as_ushort(__float2half(a));
    }
    if (t <= NPB) rp_g[bkt * 32 + t] = rp[t];
}

__device__ __forceinline__ void accum4(float4& a, uint2 u, float w) {
    __half2 p0 = *(const __half2*)&u.x;
    __half2 p1 = *(const __half2*)&u.y;
    float2 f0 = __half22float2(p0), f1 = __half22float2(p1);
    a.x = fmaf(w, f0.x, a.x); a.y = fmaf(w, f0.y, a.y);
    a.z = fmaf(w, f1.x, a.z); a.w = fmaf(w, f1.y, a.w);
}

__device__ __forceinline__ float wdec(unsigned e) {
    return __half2float(__ushort_as_half((unsigned short)(e & 0xFFFFu)));
}

// gather: one block per (bucket, dim-quarter); blk&7 pins quarter->XCD so
// each XCD's L2 works on one 3.2 MB h-slice. Sorted edge list STAGED IN LDS
// (kills the global sb->hq dependent chain); 8-lane subgroups, uint2/lane,
// 4x unroll = 4 gathers in flight per wave.
__global__ __launch_bounds__(256) void k_gather(const __half* __restrict__ h16q,
                                                const unsigned* __restrict__ gep,
                                                const int* __restrict__ rp_g,
                                                float* __restrict__ out) {
    __shared__ int rp[NPB + 1];
    __shared__ unsigned se[CAP_LDS];
    const int blk = blockIdx.x;
    const int x = blk & 7;
    const int qq = x & 3;                            // dim quarter
    const int bkt = ((blk >> 3) << 1) + (x >> 2);    // bucket
    const int t = threadIdx.x;
    if (t <= NPB) rp[t] = rp_g[bkt * 32 + t];
    __syncthreads();
    const int total = rp[NPB];
    const unsigned* sb = gep + (size_t)bkt * (NCH * CAPC);
    for (int i = t; i < total; i += 256) se[i] = sb[i];
    __syncthreads();
    const int wv = t >> 6, lane = t & 63;
    const int eg = lane >> 3;   // edge subgroup 0..7
    const int dp = lane & 7;    // uint2 index within 32-half quarter row
    const uint2* hq = (const uint2*)h16q + (size_t)qq * (N_NODES * 8) + dp;
    for (int n = wv; n < NPB; n += 4) {
        int lo = rp[n], hi = rp[n + 1];
        float4 a4 = {0.f, 0.f, 0.f, 0.f};
        int i = lo + eg;
        for (; i + 24 < hi; i += 32) {
            unsigned e0 = se[i], e1 = se[i + 8], e2 = se[i + 16], e3 = se[i + 24];
            uint2 u0 = hq[(e0 >> 16) * 8];
            uint2 u1 = hq[(e1 >> 16) * 8];
            uint2 u2 = hq[(e2 >> 16) * 8];
            uint2 u3 = hq[(e3 >> 16) * 8];
            accum4(a4, u0, wdec(e0));
            accum4(a4, u1, wdec(e1));
            accum4(a4, u2, wdec(e2));
            accum4(a4, u3, wdec(e3));
        }
        for (; i < hi; i += 8) {
            unsigned e = se[i];
            uint2 u = hq[(e >> 16) * 8];
            accum4(a4, u, wdec(e));
        }
        a4.x += __shfl_xor(a4.x, 8); a4.x += __shfl_xor(a4.x, 16); a4.x += __shfl_xor(a4.x, 32);
        a4.y += __shfl_xor(a4.y, 8); a4.y += __shfl_xor(a4.y, 16); a4.y += __shfl_xor(a4.y, 32);
        a4.z += __shfl_xor(a4.z, 8); a4.z += __shfl_xor(a4.z, 16); a4.z += __shfl_xor(a4.z, 32);
        a4.w += __shfl_xor(a4.w, 8); a4.w += __shfl_xor(a4.w, 16); a4.w += __shfl_xor(a4.w, 32);
        if (eg == 0) {
            ((float4*)out)[(size_t)(bkt * NPB + n) * 32 + qq * 8 + dp] = a4;
        }
    }
}

extern "C" void kernel_launch(void* const* d_in, const int* in_sizes, int n_in,
                              void* d_out, int out_size, void* d_ws, size_t ws_size,
                              hipStream_t stream) {
    const float* feat   = (const float*)d_in[0];
    const int*   src    = (const int*)d_in[1];
    const int*   dst    = (const int*)d_in[2];
    const float* W      = (const float*)d_in[3];
    const float* b      = (const float*)d_in[4];
    const float* attn_w = (const float*)d_in[5];
    const float* attn_b = (const float*)d_in[6];
    const float* mask   = (const float*)d_in[7];
    float* out = (float*)d_out;

    char* ws = (char*)d_ws;
    __half*   h16q  = (__half*)(ws + 0);
    float*    s_src = (float*)(ws + 12800000);
    float*    s_dst = (float*)(ws + 13000000);
    int*      cnt   = (int*)(ws + 13200000);
    unsigned* gep   = (unsigned*)(ws + 14000000);
    int*      rp_g  = (int*)(ws + 39600000);
    __half*   w16q  = (__half*)(ws + 39856000);
    float*    waSD  = (float*)(ws + 39888768);
    float*    cst   = (float*)(ws + 39889792);

    k_prep<<<41, 256, 0, stream>>>(W, b, attn_w, w16q, waSD, cst);
    k_fusedA<<<PLACE_BLOCKS + PROJ_BLOCKS, 512, 0, stream>>>(
        feat, b, mask, src, dst, h16q, s_src, s_dst, cnt, gep, w16q, waSD, cst);
    k_sort<<<NB, 256, 0, stream>>>(s_src, s_dst, attn_b, cnt, gep, rp_g);
    k_gather<<<NB * 4, 256, 0, stream>>>(h16q, gep, rp_g, out);
}

// Round 2
// 185.992 us; speedup vs baseline: 1.1946x; 1.0094x over previous
//
#include <hip/hip_runtime.h>
#include <hip/hip_fp16.h>
#include <math.h>

#define N_NODES 50000
#define N_EDGES 1600000
#define NB 2000      // dst buckets; NB*NPB == N_NODES
#define NPB 25       // dst nodes per bucket (dstLocal in 5 bits)
#define NCH 100      // edge chunks
#define EPC 16000    // edges per chunk
#define CAPC 32      // slots per (bucket,chunk) cell: Poisson(8) + ~8 sigma
#define CAP_LDS 1280 // max edges per bucket (mean 800, +17 sigma)
#define SPLIT 8      // place: blocks per chunk (bucket-range partition)
#define BPS (NB / SPLIT)                        // 250
#define PLACE_BLOCKS (NCH * SPLIT)              // 800
#define PROJ_BLOCKS ((N_NODES + 31) / 32)       // 1563

typedef _Float16 f16x8 __attribute__((ext_vector_type(8)));
typedef float f32x4 __attribute__((ext_vector_type(4)));

// ---- workspace layout (bytes) ----
// h16q   : 0           12,800,000  __half QUARTER-MAJOR [4][N_NODES][32]
// s_src  : 12,800,000     200,000  float[N]
// s_dst  : 13,000,000     200,000  float[N]
// cnt    : 13,200,000     800,000  int[NCH*NB] (chunk-major)
// gep    : 14,000,000  25,600,000  u32[NB*3200]; cells, then overwritten
//                                  in-place by k_sort with sorted (src<<16)|a16
// rp_g   : 39,600,000     256,000  int[NB*32] per-bucket rowptr (26 used)
// w16q   : 39,856,000      32,768  __half[16384] W in MFMA B-fragment order
// waSD   : 39,888,768       1,024  float[256]: waS[128] then waD[128]
// cst    : 39,889,792           8  float[2]: bS, bD
// total ~39.89 MB

// Tiny prep kernel: W -> f16 B-fragment layout + folded attention vectors.
//   waS = W @ attn_w[:128], waD = W @ attn_w[128:], bS = b.aS, bD = b.aD
// (s_src = h@aS = x_masked@waS + bS by linearity -> dots decouple from GEMM)
__global__ __launch_bounds__(256) void k_prep(const float* __restrict__ W,
                                              const float* __restrict__ b,
                                              const float* __restrict__ attn_w,
                                              __half* __restrict__ w16q,
                                              float* __restrict__ waSD,
                                              float* __restrict__ cst) {
    const int blk = blockIdx.x, t = threadIdx.x;
    if (blk < 8) {
        // waS/waD: row k = blk*16 + (t>>4), 16 lanes per row, shfl-reduce
        const int k = blk * 16 + (t >> 4), sub = t & 15;
        const float4* W4 = (const float4*)W;
        float4 w0 = W4[k * 32 + sub * 2];
        float4 w1 = W4[k * 32 + sub * 2 + 1];
        const int j0 = sub * 8;
        float pS = w0.x * attn_w[j0]     + w0.y * attn_w[j0 + 1]
                 + w0.z * attn_w[j0 + 2] + w0.w * attn_w[j0 + 3]
                 + w1.x * attn_w[j0 + 4] + w1.y * attn_w[j0 + 5]
                 + w1.z * attn_w[j0 + 6] + w1.w * attn_w[j0 + 7];
        float pD = w0.x * attn_w[128 + j0]     + w0.y * attn_w[128 + j0 + 1]
                 + w0.z * attn_w[128 + j0 + 2] + w0.w * attn_w[128 + j0 + 3]
                 + w1.x * attn_w[128 + j0 + 4] + w1.y * attn_w[128 + j0 + 5]
                 + w1.z * attn_w[128 + j0 + 6] + w1.w * attn_w[128 + j0 + 7];
        pS += __shfl_down(pS, 8); pS += __shfl_down(pS, 4);
        pS += __shfl_down(pS, 2); pS += __shfl_down(pS, 1);
        pD += __shfl_down(pD, 8); pD += __shfl_down(pD, 4);
        pD += __shfl_down(pD, 2); pD += __shfl_down(pD, 1);
        if (sub == 0) { waSD[k] = pS; waSD[128 + k] = pD; }
    } else if (blk < 40) {
        // w16q element e = ((ct*4+kb)*64 + l)*8 + j  holds
        //   (half) W[kb*32 + (l>>4)*8 + j][ct*16 + (l&15)]
        for (int e = (blk - 8) * 256 + t; e < 16384; e += 8192) {
            int j = e & 7, l = (e >> 3) & 63, kb = (e >> 9) & 3, ct = e >> 11;
            int k = kb * 32 + (l >> 4) * 8 + j;
            int c = ct * 16 + (l & 15);
            w16q[e] = __float2half(W[k * 128 + c]);
        }
    } else if (t < 64) {
        float vS = b[t] * attn_w[t]       + b[t + 64] * attn_w[t + 64];
        float vD = b[t] * attn_w[128 + t] + b[t + 64] * attn_w[192 + t];
        for (int off = 32; off; off >>= 1) {
            vS += __shfl_down(vS, off);
            vD += __shfl_down(vD, off);
        }
        if (t == 0) { cst[0] = vS; cst[1] = vD; }
    }
}

// Fused block-specialized kernel. Union LDS = 33 KB -> 4 blocks/CU for BOTH
// paths (round-9's 66 KB union capped everything at 2/CU - the fix).
//   blocks [0, 800):    edge binning, chunk c = blk>>3, quartile sp = blk&7
//   blocks [800, 2363): MFMA projection + attention dots (proj LDS 9.7 KB)
__global__ __launch_bounds__(512) void k_fusedA(const float* __restrict__ feat,
                                                const float* __restrict__ b,
                                                const float* __restrict__ mask,
                                                const int* __restrict__ src,
                                                const int* __restrict__ dst,
                                                __half* __restrict__ h16q,
                                                float* __restrict__ s_src,
                                                float* __restrict__ s_dst,
                                                int* __restrict__ cnt,
                                                unsigned* __restrict__ gep,
                                                const __half* __restrict__ w16q,
                                                const float* __restrict__ waSD,
                                                const float* __restrict__ cst) {
    __shared__ __align__(16) char smem[33024];  // place 33 KB / proj 9.7 KB
    const int blk = blockIdx.x;
    const int t = threadIdx.x;

    if (blk < PLACE_BLOCKS) {
        // ---------------- place path (unchanged) ----------------
        int* cur = (int*)smem;                        // [BPS] 1000 B
        unsigned* lcell = (unsigned*)(smem + 1024);   // [BPS*CAPC] 32000 B
        const int c = blk >> 3, sp = blk & 7;
        const int b0 = sp * BPS;
        for (int i = t; i < BPS; i += 512) cur[i] = 0;
        __syncthreads();
        const int q0 = c * (EPC / 4);
        for (int q = t; q < EPC / 4; q += 512) {
            int4 s4 = ((const int4*)src)[q0 + q];
            int4 d4 = ((const int4*)dst)[q0 + q];
            int ss[4] = {s4.x, s4.y, s4.z, s4.w};
            int dd[4] = {d4.x, d4.y, d4.z, d4.w};
#pragma unroll
            for (int k = 0; k < 4; k++) {
                int d = dd[k];
                int bkt = d / NPB;           // magic-mul
                if (bkt >= b0 && bkt < b0 + BPS) {
                    int dl = d - bkt * NPB;
                    int lb = bkt - b0;
                    int r = atomicAdd(&cur[lb], 1);
                    if (r < CAPC)
                        lcell[lb * CAPC + r] = ((unsigned)ss[k] << 5) | (unsigned)dl;
                }
            }
        }
        __syncthreads();
        // coalesced cell write-out: 8 uint4 per cell (128 B, one full line)
        const uint4* lc4 = (const uint4*)lcell;
        uint4* gp4 = (uint4*)gep;
        for (int idx = t; idx < BPS * (CAPC / 4); idx += 512) {
            int i = idx >> 3, q = idx & 7;
            gp4[((size_t)(b0 + i) * NCH + c) * 8 + q] = lc4[idx];
        }
        for (int i = t; i < BPS; i += 512) cnt[c * NB + b0 + i] = min(cur[i], CAPC);
    } else {
        // ---------------- MFMA projection + dots path ----------------
        // LDS: a16[32][128] halves XOR-swizzled (byte ^= (row&7)<<4) : 8192 B
        //      sAW @8192 (512 B), sAD @8704 (512 B), sig @9216 (512 B)
        float* sAW = (float*)(smem + 8192);
        float* sAD = (float*)(smem + 8704);
        float* sig = (float*)(smem + 9216);
        const int bb = blk - PLACE_BLOCKS;
        const int row0 = bb * 32;
        if (t < 128) {
            sig[t] = 1.f / (1.f + expf(-mask[t]));
            sAW[t] = waSD[t];
            sAD[t] = waSD[128 + t];
        }
        __syncthreads();
        // feat tile: float4 load -> mask -> f16 -> swizzled LDS (8 B stores)
        for (int idx = t; idx < 32 * 32; idx += 512) {
            int r = idx >> 5, c4 = idx & 31;
            int grow = row0 + r;
            float4 f;
            if (grow < N_NODES) f = ((const float4*)feat)[grow * 32 + c4];
            else f = make_float4(0.f, 0.f, 0.f, 0.f);
            int c = c4 * 4;
            ushort4 pk;
            pk.x = __half_as_ushort(__float2half(f.x * sig[c]));
            pk.y = __half_as_ushort(__float2half(f.y * sig[c + 1]));
            pk.z = __half_as_ushort(__float2half(f.z * sig[c + 2]));
            pk.w = __half_as_ushort(__float2half(f.w * sig[c + 3]));
            int byte = (r * 256 + c4 * 8) ^ ((r & 7) << 4);
            *(ushort4*)(smem + byte) = pk;
        }
        __syncthreads();
        // wave wv owns col-tile ct=wv (cols wv*16..+15); row-tiles m=0,1.
        // A frag: lane l holds A[l&15][(l>>4)*8 + j]; B frag from w16q.
        const int wv = t >> 6, l = t & 63;
        const int lr = l & 15, lk = l >> 4;
        const f16x8* wq = (const f16x8*)w16q;
        f32x4 acc0 = {0.f, 0.f, 0.f, 0.f};
        f32x4 acc1 = {0.f, 0.f, 0.f, 0.f};
#pragma unroll
        for (int kb = 0; kb < 4; kb++) {
            f16x8 Bf = wq[(wv * 4 + kb) * 64 + l];
            int co = kb * 64 + lk * 16;                     // k-slice byte off
            f16x8 A0 = *(const f16x8*)(smem + ((lr * 256 + co) ^ ((lr & 7) << 4)));
            f16x8 A1 = *(const f16x8*)(smem + (((16 + lr) * 256 + co) ^ ((lr & 7) << 4)));
            acc0 = __builtin_amdgcn_mfma_f32_16x16x32_f16(A0, Bf, acc0, 0, 0, 0);
            acc1 = __builtin_amdgcn_mfma_f32_16x16x32_f16(A1, Bf, acc1, 0, 0, 0);
        }
        // dots: s_src/s_dst from a16 directly (folded waS/waD) - independent
        // of the MFMA results, no extra barrier.
        {
            const int r2 = t >> 4, sub = t & 15;
            f16x8 xv = *(const f16x8*)(smem + ((r2 * 256 + sub * 16) ^ ((r2 & 7) << 4)));
            float ss = 0.f, sd = 0.f;
#pragma unroll
            for (int q = 0; q < 8; q++) {
                float v = (float)xv[q];
                int jj = sub * 8 + q;
                ss = fmaf(v, sAW[jj], ss);
                sd = fmaf(v, sAD[jj], sd);
            }
            ss += __shfl_down(ss, 8); ss += __shfl_down(ss, 4);
            ss += __shfl_down(ss, 2); ss += __shfl_down(ss, 1);
            sd += __shfl_down(sd, 8); sd += __shfl_down(sd, 4);
            sd += __shfl_down(sd, 2); sd += __shfl_down(sd, 1);
            int grow = row0 + r2;
            if (sub == 0 && grow < N_NODES) {
                s_src[grow] = ss + cst[0];
                s_dst[grow] = sd + cst[1];
            }
        }
        // epilogue: C frag col = lr, row = lk*4 + reg; add bias, store fp16
        const float bj = b[wv * 16 + lr];
        __half* hp = h16q + (size_t)(wv >> 1) * (N_NODES * 32) + ((wv & 1) * 16 + lr);
#pragma unroll
        for (int reg = 0; reg < 4; reg++) {
            int n0 = row0 + lk * 4 + reg;
            if (n0 < N_NODES) hp[(size_t)n0 * 32] = __float2half(acc0[reg] + bj);
            int n1 = n0 + 16;
            if (n1 < N_NODES) hp[(size_t)n1 * 32] = __float2half(acc1[reg] + bj);
        }
    }
}

// per-bucket: DENSE coalesced cell read -> LDS counting sort by dstLocal ->
// exp weights -> per-node denom (LDS atomics) -> pre-normalized a=w/denom
// packed (src<<16)|fp16(a), written in place over own gep region + rowptr.
__global__ __launch_bounds__(256) void k_sort(const float* __restrict__ s_src,
                                              const float* __restrict__ s_dst,
                                              const float* __restrict__ attn_b,
                                              const int* __restrict__ cnt,
                                              unsigned* gep,
                                              int* __restrict__ rp_g) {
    __shared__ unsigned raw[CAP_LDS];
    __shared__ unsigned srt[CAP_LDS];   // (src<<16)|dl during pass A
    __shared__ float wbuf[CAP_LDS];
    __shared__ int ccnt[NCH];
    __shared__ int coff[NCH];
    __shared__ int hist[NPB];
    __shared__ int rp[NPB + 1];
    __shared__ int curn[NPB];
    __shared__ float sdl[NPB];
    __shared__ float dsum[NPB];
    __shared__ float dinv[NPB];
    __shared__ int totsh;
    const int bkt = blockIdx.x;
    const int t = threadIdx.x;
    if (t < NCH) ccnt[t] = cnt[t * NB + bkt];
    if (t < NPB) { hist[t] = 0; dsum[t] = 0.f; sdl[t] = s_dst[bkt * NPB + t]; }
    __syncthreads();
    if (t < 64) {   // exclusive scan of 100 cell counts (wave 0)
        int i0 = 2 * t, i1 = 2 * t + 1;
        int a0 = (i0 < NCH) ? ccnt[i0] : 0;
        int a1 = (i1 < NCH) ? ccnt[i1] : 0;
        int s = a0 + a1, incl = s;
#pragma unroll
        for (int off = 1; off < 64; off <<= 1) {
            int v = __shfl_up(incl, off);
            if (t >= off) incl += v;
        }
        int excl = incl - s;
        if (i0 < NCH) coff[i0] = excl;
        if (i1 < NCH) coff[i1] = excl + a0;
        if (t == 63) totsh = incl;
    }
    __syncthreads();
    int total = totsh;
    if (total > CAP_LDS) total = CAP_LDS;
    unsigned* gb = gep + (size_t)bkt * (NCH * CAPC);
    // dense cell read: full-line coalesced; predicate gates only the LDS write
    for (int i = t; i < NCH * CAPC; i += 256) {
        unsigned e = gb[i];
        int cell = i >> 5, slot = i & 31;
        if (slot < ccnt[cell]) {
            int pos = coff[cell] + slot;
            if (pos < CAP_LDS) {
                raw[pos] = e;
                atomicAdd(&hist[e & 31], 1);
            }
        }
    }
    __syncthreads();
    if (t == 0) {
        int run = 0;
        for (int j = 0; j < NPB; j++) { rp[j] = run; curn[j] = run; run += hist[j]; }
        rp[NPB] = run;
    }
    __syncthreads();
    const float ab = attn_b[0];
    for (int i = t; i < total; i += 256) {   // pass A: exp + denom accumulate
        unsigned e = raw[i];
        int dl = e & 31;
        int s = (int)(e >> 5);
        float sc = s_src[s] + sdl[dl] + ab;
        sc = sc >= 0.f ? sc : 0.01f * sc;   // leaky_relu; |sc| small, exp safe
        float w = expf(sc);
        int pos = atomicAdd(&curn[dl], 1);
        srt[pos] = ((unsigned)s << 16) | (unsigned)dl;
        wbuf[pos] = w;
        atomicAdd(&dsum[dl], w);
    }
    __syncthreads();
    if (t < NPB) dinv[t] = dsum[t] > 0.f ? 1.f / dsum[t] : 0.f;
    __syncthreads();
    for (int i = t; i < total; i += 256) {   // pass B: normalize + pack
        unsigned e = srt[i];
        float a = wbuf[i] * dinv[e & 31];
        gb[i] = (e & 0xFFFF0000u) | (unsigned)__half_as_ushort(__float2half(a));
    }
    if (t <= NPB) rp_g[bkt * 32 + t] = rp[t];
}

__device__ __forceinline__ void accum4(float4& a, uint2 u, float w) {
    __half2 p0 = *(const __half2*)&u.x;
    __half2 p1 = *(const __half2*)&u.y;
    float2 f0 = __half22float2(p0), f1 = __half22float2(p1);
    a.x = fmaf(w, f0.x, a.x); a.y = fmaf(w, f0.y, a.y);
    a.z = fmaf(w, f1.x, a.z); a.w = fmaf(w, f1.y, a.w);
}

__device__ __forceinline__ float wdec(unsigned e) {
    return __half2float(__ushort_as_half((unsigned short)(e & 0xFFFFu)));
}

// gather: one block per (bucket, dim-quarter); blk&7 pins quarter->XCD so
// each XCD's L2 works on one 3.2 MB h-slice. Sorted edge list STAGED IN LDS
// (kills the global sb->hq dependent chain); 8-lane subgroups, uint2/lane.
// Inner loop is ALWAYS 4-deep: tail slots are predicated to edge-word 0
// (weight fp16(0) -> exact zero contribution, src row 0 load is L1-hot).
// This keeps 4 gathers in flight through the tail windows - the old scalar
// remainder loop exposed a full L2 latency per leftover 8-edge group.
__global__ __launch_bounds__(256) void k_gather(const __half* __restrict__ h16q,
                                                const unsigned* __restrict__ gep,
                                                const int* __restrict__ rp_g,
                                                float* __restrict__ out) {
    __shared__ int rp[NPB + 1];
    __shared__ unsigned se[CAP_LDS];
    const int blk = blockIdx.x;
    const int x = blk & 7;
    const int qq = x & 3;                            // dim quarter
    const int bkt = ((blk >> 3) << 1) + (x >> 2);    // bucket
    const int t = threadIdx.x;
    if (t <= NPB) rp[t] = rp_g[bkt * 32 + t];
    __syncthreads();
    const int total = rp[NPB];
    const unsigned* sb = gep + (size_t)bkt * (NCH * CAPC);
    for (int i = t; i < total; i += 256) se[i] = sb[i];
    __syncthreads();
    const int wv = t >> 6, lane = t & 63;
    const int eg = lane >> 3;   // edge subgroup 0..7
    const int dp = lane & 7;    // uint2 index within 32-half quarter row
    const uint2* hq = (const uint2*)h16q + (size_t)qq * (N_NODES * 8) + dp;
    for (int n = wv; n < NPB; n += 4) {
        int lo = rp[n], hi = rp[n + 1];
        float4 a4 = {0.f, 0.f, 0.f, 0.f};
        for (int i = lo + eg; i < hi; i += 32) {
            unsigned e0 = se[i];
            unsigned e1 = (i + 8  < hi) ? se[i + 8]  : 0u;
            unsigned e2 = (i + 16 < hi) ? se[i + 16] : 0u;
            unsigned e3 = (i + 24 < hi) ? se[i + 24] : 0u;
            uint2 u0 = hq[(e0 >> 16) * 8];
            uint2 u1 = hq[(e1 >> 16) * 8];
            uint2 u2 = hq[(e2 >> 16) * 8];
            uint2 u3 = hq[(e3 >> 16) * 8];
            accum4(a4, u0, wdec(e0));
            accum4(a4, u1, wdec(e1));
            accum4(a4, u2, wdec(e2));
            accum4(a4, u3, wdec(e3));
        }
        a4.x += __shfl_xor(a4.x, 8); a4.x += __shfl_xor(a4.x, 16); a4.x += __shfl_xor(a4.x, 32);
        a4.y += __shfl_xor(a4.y, 8); a4.y += __shfl_xor(a4.y, 16); a4.y += __shfl_xor(a4.y, 32);
        a4.z += __shfl_xor(a4.z, 8); a4.z += __shfl_xor(a4.z, 16); a4.z += __shfl_xor(a4.z, 32);
        a4.w += __shfl_xor(a4.w, 8); a4.w += __shfl_xor(a4.w, 16); a4.w += __shfl_xor(a4.w, 32);
        if (eg == 0) {
            ((float4*)out)[(size_t)(bkt * NPB + n) * 32 + qq * 8 + dp] = a4;
        }
    }
}

extern "C" void kernel_launch(void* const* d_in, const int* in_sizes, int n_in,
                              void* d_out, int out_size, void* d_ws, size_t ws_size,
                              hipStream_t stream) {
    const float* feat   = (const float*)d_in[0];
    const int*   src    = (const int*)d_in[1];
    const int*   dst    = (const int*)d_in[2];
    const float* W      = (const float*)d_in[3];
    const float* b      = (const float*)d_in[4];
    const float* attn_w = (const float*)d_in[5];
    const float* attn_b = (const float*)d_in[6];
    const float* mask   = (const float*)d_in[7];
    float* out = (float*)d_out;

    char* ws = (char*)d_ws;
    __half*   h16q  = (__half*)(ws + 0);
    float*    s_src = (float*)(ws + 12800000);
    float*    s_dst = (float*)(ws + 13000000);
    int*      cnt   = (int*)(ws + 13200000);
    unsigned* gep   = (unsigned*)(ws + 14000000);
    int*      rp_g  = (int*)(ws + 39600000);
    __half*   w16q  = (__half*)(ws + 39856000);
    float*    waSD  = (float*)(ws + 39888768);
    float*    cst   = (float*)(ws + 39889792);

    k_prep<<<41, 256, 0, stream>>>(W, b, attn_w, w16q, waSD, cst);
    k_fusedA<<<PLACE_BLOCKS + PROJ_BLOCKS, 512, 0, stream>>>(
        feat, b, mask, src, dst, h16q, s_src, s_dst, cnt, gep, w16q, waSD, cst);
    k_sort<<<NB, 256, 0, stream>>>(s_src, s_dst, attn_b, cnt, gep, rp_g);
    k_gather<<<NB * 4, 256, 0, stream>>>(h16q, gep, rp_g, out);
}

// Round 3
// 176.541 us; speedup vs baseline: 1.2585x; 1.0535x over previous
//
#include <hip/hip_runtime.h>
#include <hip/hip_fp16.h>
#include <math.h>

#define N_NODES 50000
#define N_EDGES 1600000
#define NB 2000      // dst buckets; NB*NPB == N_NODES
#define NPB 25       // dst nodes per bucket (dstLocal in 5 bits)
#define NCH 100      // edge chunks
#define EPC 16000    // edges per chunk
#define CAPC 32      // slots per (bucket,chunk) cell: Poisson(8) + ~8 sigma
#define CAP_LDS 1280 // max edges per bucket (mean 800, +17 sigma)
#define SPLIT 8      // place: blocks per chunk (bucket-range partition)
#define BPS (NB / SPLIT)                        // 250
#define PLACE_BLOCKS (NCH * SPLIT)              // 800
#define PROJ_BLOCKS ((N_NODES + 31) / 32)       // 1563
#define NBG 5        // gather: buckets per block
#define NGRP (NBG * NPB)                        // 125 node-groups per block
#define GQ_BLOCKS ((NB / (NBG * 2)) * 8)        // 1600

typedef _Float16 f16x8 __attribute__((ext_vector_type(8)));
typedef float f32x4 __attribute__((ext_vector_type(4)));

// ---- workspace layout (bytes) ----
// h16q   : 0           12,800,000  __half QUARTER-MAJOR [4][N_NODES][32]
// s_src  : 12,800,000     200,000  float[N]
// s_dst  : 13,000,000     200,000  float[N]
// cnt    : 13,200,000     800,000  int[NCH*NB] (chunk-major)
// gep    : 14,000,000  25,600,000  u32[NB*3200]; cells, then overwritten
//                                  in-place by k_sort with sorted (src<<16)|a16
// rp_g   : 39,600,000     256,000  int[NB*32] per-bucket rowptr (26 used)
// w16q   : 39,856,000      32,768  __half[16384] W in MFMA B-fragment order
// waSD   : 39,888,768       1,024  float[256]: waS[128] then waD[128]
// cst    : 39,889,792           8  float[2]: bS, bD
// total ~39.89 MB

// Tiny prep kernel: W -> f16 B-fragment layout + folded attention vectors.
//   waS = W @ attn_w[:128], waD = W @ attn_w[128:], bS = b.aS, bD = b.aD
// (s_src = h@aS = x_masked@waS + bS by linearity -> dots decouple from GEMM)
__global__ __launch_bounds__(256) void k_prep(const float* __restrict__ W,
                                              const float* __restrict__ b,
                                              const float* __restrict__ attn_w,
                                              __half* __restrict__ w16q,
                                              float* __restrict__ waSD,
                                              float* __restrict__ cst) {
    const int blk = blockIdx.x, t = threadIdx.x;
    if (blk < 8) {
        // waS/waD: row k = blk*16 + (t>>4), 16 lanes per row, shfl-reduce
        const int k = blk * 16 + (t >> 4), sub = t & 15;
        const float4* W4 = (const float4*)W;
        float4 w0 = W4[k * 32 + sub * 2];
        float4 w1 = W4[k * 32 + sub * 2 + 1];
        const int j0 = sub * 8;
        float pS = w0.x * attn_w[j0]     + w0.y * attn_w[j0 + 1]
                 + w0.z * attn_w[j0 + 2] + w0.w * attn_w[j0 + 3]
                 + w1.x * attn_w[j0 + 4] + w1.y * attn_w[j0 + 5]
                 + w1.z * attn_w[j0 + 6] + w1.w * attn_w[j0 + 7];
        float pD = w0.x * attn_w[128 + j0]     + w0.y * attn_w[128 + j0 + 1]
                 + w0.z * attn_w[128 + j0 + 2] + w0.w * attn_w[128 + j0 + 3]
                 + w1.x * attn_w[128 + j0 + 4] + w1.y * attn_w[128 + j0 + 5]
                 + w1.z * attn_w[128 + j0 + 6] + w1.w * attn_w[128 + j0 + 7];
        pS += __shfl_down(pS, 8); pS += __shfl_down(pS, 4);
        pS += __shfl_down(pS, 2); pS += __shfl_down(pS, 1);
        pD += __shfl_down(pD, 8); pD += __shfl_down(pD, 4);
        pD += __shfl_down(pD, 2); pD += __shfl_down(pD, 1);
        if (sub == 0) { waSD[k] = pS; waSD[128 + k] = pD; }
    } else if (blk < 40) {
        // w16q element e = ((ct*4+kb)*64 + l)*8 + j  holds
        //   (half) W[kb*32 + (l>>4)*8 + j][ct*16 + (l&15)]
        for (int e = (blk - 8) * 256 + t; e < 16384; e += 8192) {
            int j = e & 7, l = (e >> 3) & 63, kb = (e >> 9) & 3, ct = e >> 11;
            int k = kb * 32 + (l >> 4) * 8 + j;
            int c = ct * 16 + (l & 15);
            w16q[e] = __float2half(W[k * 128 + c]);
        }
    } else if (t < 64) {
        float vS = b[t] * attn_w[t]       + b[t + 64] * attn_w[t + 64];
        float vD = b[t] * attn_w[128 + t] + b[t + 64] * attn_w[192 + t];
        for (int off = 32; off; off >>= 1) {
            vS += __shfl_down(vS, off);
            vD += __shfl_down(vD, off);
        }
        if (t == 0) { cst[0] = vS; cst[1] = vD; }
    }
}

// Fused block-specialized kernel. Union LDS = 33 KB -> 4 blocks/CU for BOTH
// paths (round-9's 66 KB union capped everything at 2/CU - the fix).
//   blocks [0, 800):    edge binning, chunk c = blk>>3, quartile sp = blk&7
//   blocks [800, 2363): MFMA projection + attention dots (proj LDS 9.7 KB)
__global__ __launch_bounds__(512) void k_fusedA(const float* __restrict__ feat,
                                                const float* __restrict__ b,
                                                const float* __restrict__ mask,
                                                const int* __restrict__ src,
                                                const int* __restrict__ dst,
                                                __half* __restrict__ h16q,
                                                float* __restrict__ s_src,
                                                float* __restrict__ s_dst,
                                                int* __restrict__ cnt,
                                                unsigned* __restrict__ gep,
                                                const __half* __restrict__ w16q,
                                                const float* __restrict__ waSD,
                                                const float* __restrict__ cst) {
    __shared__ __align__(16) char smem[33024];  // place 33 KB / proj 9.7 KB
    const int blk = blockIdx.x;
    const int t = threadIdx.x;

    if (blk < PLACE_BLOCKS) {
        // ---------------- place path (unchanged) ----------------
        int* cur = (int*)smem;                        // [BPS] 1000 B
        unsigned* lcell = (unsigned*)(smem + 1024);   // [BPS*CAPC] 32000 B
        const int c = blk >> 3, sp = blk & 7;
        const int b0 = sp * BPS;
        for (int i = t; i < BPS; i += 512) cur[i] = 0;
        __syncthreads();
        const int q0 = c * (EPC / 4);
        for (int q = t; q < EPC / 4; q += 512) {
            int4 s4 = ((const int4*)src)[q0 + q];
            int4 d4 = ((const int4*)dst)[q0 + q];
            int ss[4] = {s4.x, s4.y, s4.z, s4.w};
            int dd[4] = {d4.x, d4.y, d4.z, d4.w};
#pragma unroll
            for (int k = 0; k < 4; k++) {
                int d = dd[k];
                int bkt = d / NPB;           // magic-mul
                if (bkt >= b0 && bkt < b0 + BPS) {
                    int dl = d - bkt * NPB;
                    int lb = bkt - b0;
                    int r = atomicAdd(&cur[lb], 1);
                    if (r < CAPC)
                        lcell[lb * CAPC + r] = ((unsigned)ss[k] << 5) | (unsigned)dl;
                }
            }
        }
        __syncthreads();
        // coalesced cell write-out: 8 uint4 per cell (128 B, one full line)
        const uint4* lc4 = (const uint4*)lcell;
        uint4* gp4 = (uint4*)gep;
        for (int idx = t; idx < BPS * (CAPC / 4); idx += 512) {
            int i = idx >> 3, q = idx & 7;
            gp4[((size_t)(b0 + i) * NCH + c) * 8 + q] = lc4[idx];
        }
        for (int i = t; i < BPS; i += 512) cnt[c * NB + b0 + i] = min(cur[i], CAPC);
    } else {
        // ---------------- MFMA projection + dots path ----------------
        // LDS: a16[32][128] halves XOR-swizzled (byte ^= (row&7)<<4) : 8192 B
        //      sAW @8192 (512 B), sAD @8704 (512 B), sig @9216 (512 B)
        float* sAW = (float*)(smem + 8192);
        float* sAD = (float*)(smem + 8704);
        float* sig = (float*)(smem + 9216);
        const int bb = blk - PLACE_BLOCKS;
        const int row0 = bb * 32;
        if (t < 128) {
            sig[t] = 1.f / (1.f + expf(-mask[t]));
            sAW[t] = waSD[t];
            sAD[t] = waSD[128 + t];
        }
        __syncthreads();
        // feat tile: float4 load -> mask -> f16 -> swizzled LDS (8 B stores)
        for (int idx = t; idx < 32 * 32; idx += 512) {
            int r = idx >> 5, c4 = idx & 31;
            int grow = row0 + r;
            float4 f;
            if (grow < N_NODES) f = ((const float4*)feat)[grow * 32 + c4];
            else f = make_float4(0.f, 0.f, 0.f, 0.f);
            int c = c4 * 4;
            ushort4 pk;
            pk.x = __half_as_ushort(__float2half(f.x * sig[c]));
            pk.y = __half_as_ushort(__float2half(f.y * sig[c + 1]));
            pk.z = __half_as_ushort(__float2half(f.z * sig[c + 2]));
            pk.w = __half_as_ushort(__float2half(f.w * sig[c + 3]));
            int byte = (r * 256 + c4 * 8) ^ ((r & 7) << 4);
            *(ushort4*)(smem + byte) = pk;
        }
        __syncthreads();
        // wave wv owns col-tile ct=wv (cols wv*16..+15); row-tiles m=0,1.
        // A frag: lane l holds A[l&15][(l>>4)*8 + j]; B frag from w16q.
        const int wv = t >> 6, l = t & 63;
        const int lr = l & 15, lk = l >> 4;
        const f16x8* wq = (const f16x8*)w16q;
        f32x4 acc0 = {0.f, 0.f, 0.f, 0.f};
        f32x4 acc1 = {0.f, 0.f, 0.f, 0.f};
#pragma unroll
        for (int kb = 0; kb < 4; kb++) {
            f16x8 Bf = wq[(wv * 4 + kb) * 64 + l];
            int co = kb * 64 + lk * 16;                     // k-slice byte off
            f16x8 A0 = *(const f16x8*)(smem + ((lr * 256 + co) ^ ((lr & 7) << 4)));
            f16x8 A1 = *(const f16x8*)(smem + (((16 + lr) * 256 + co) ^ ((lr & 7) << 4)));
            acc0 = __builtin_amdgcn_mfma_f32_16x16x32_f16(A0, Bf, acc0, 0, 0, 0);
            acc1 = __builtin_amdgcn_mfma_f32_16x16x32_f16(A1, Bf, acc1, 0, 0, 0);
        }
        // dots: s_src/s_dst from a16 directly (folded waS/waD) - independent
        // of the MFMA results, no extra barrier.
        {
            const int r2 = t >> 4, sub = t & 15;
            f16x8 xv = *(const f16x8*)(smem + ((r2 * 256 + sub * 16) ^ ((r2 & 7) << 4)));
            float ss = 0.f, sd = 0.f;
#pragma unroll
            for (int q = 0; q < 8; q++) {
                float v = (float)xv[q];
                int jj = sub * 8 + q;
                ss = fmaf(v, sAW[jj], ss);
                sd = fmaf(v, sAD[jj], sd);
            }
            ss += __shfl_down(ss, 8); ss += __shfl_down(ss, 4);
            ss += __shfl_down(ss, 2); ss += __shfl_down(ss, 1);
            sd += __shfl_down(sd, 8); sd += __shfl_down(sd, 4);
            sd += __shfl_down(sd, 2); sd += __shfl_down(sd, 1);
            int grow = row0 + r2;
            if (sub == 0 && grow < N_NODES) {
                s_src[grow] = ss + cst[0];
                s_dst[grow] = sd + cst[1];
            }
        }
        // epilogue: C frag col = lr, row = lk*4 + reg; add bias, store fp16
        const float bj = b[wv * 16 + lr];
        __half* hp = h16q + (size_t)(wv >> 1) * (N_NODES * 32) + ((wv & 1) * 16 + lr);
#pragma unroll
        for (int reg = 0; reg < 4; reg++) {
            int n0 = row0 + lk * 4 + reg;
            if (n0 < N_NODES) hp[(size_t)n0 * 32] = __float2half(acc0[reg] + bj);
            int n1 = n0 + 16;
            if (n1 < N_NODES) hp[(size_t)n1 * 32] = __float2half(acc1[reg] + bj);
        }
    }
}

// per-bucket: DENSE coalesced cell read -> LDS counting sort by dstLocal ->
// exp weights -> per-node denom (LDS atomics) -> pre-normalized a=w/denom
// packed (src<<16)|fp16(a), written in place over own gep region + rowptr.
__global__ __launch_bounds__(256) void k_sort(const float* __restrict__ s_src,
                                              const float* __restrict__ s_dst,
                                              const float* __restrict__ attn_b,
                                              const int* __restrict__ cnt,
                                              unsigned* gep,
                                              int* __restrict__ rp_g) {
    __shared__ unsigned raw[CAP_LDS];
    __shared__ unsigned srt[CAP_LDS];   // (src<<16)|dl during pass A
    __shared__ float wbuf[CAP_LDS];
    __shared__ int ccnt[NCH];
    __shared__ int coff[NCH];
    __shared__ int hist[NPB];
    __shared__ int rp[NPB + 1];
    __shared__ int curn[NPB];
    __shared__ float sdl[NPB];
    __shared__ float dsum[NPB];
    __shared__ float dinv[NPB];
    __shared__ int totsh;
    const int bkt = blockIdx.x;
    const int t = threadIdx.x;
    if (t < NCH) ccnt[t] = cnt[t * NB + bkt];
    if (t < NPB) { hist[t] = 0; dsum[t] = 0.f; sdl[t] = s_dst[bkt * NPB + t]; }
    __syncthreads();
    if (t < 64) {   // exclusive scan of 100 cell counts (wave 0)
        int i0 = 2 * t, i1 = 2 * t + 1;
        int a0 = (i0 < NCH) ? ccnt[i0] : 0;
        int a1 = (i1 < NCH) ? ccnt[i1] : 0;
        int s = a0 + a1, incl = s;
#pragma unroll
        for (int off = 1; off < 64; off <<= 1) {
            int v = __shfl_up(incl, off);
            if (t >= off) incl += v;
        }
        int excl = incl - s;
        if (i0 < NCH) coff[i0] = excl;
        if (i1 < NCH) coff[i1] = excl + a0;
        if (t == 63) totsh = incl;
    }
    __syncthreads();
    int total = totsh;
    if (total > CAP_LDS) total = CAP_LDS;
    unsigned* gb = gep + (size_t)bkt * (NCH * CAPC);
    // dense cell read: full-line coalesced; predicate gates only the LDS write
    for (int i = t; i < NCH * CAPC; i += 256) {
        unsigned e = gb[i];
        int cell = i >> 5, slot = i & 31;
        if (slot < ccnt[cell]) {
            int pos = coff[cell] + slot;
            if (pos < CAP_LDS) {
                raw[pos] = e;
                atomicAdd(&hist[e & 31], 1);
            }
        }
    }
    __syncthreads();
    if (t == 0) {
        int run = 0;
        for (int j = 0; j < NPB; j++) { rp[j] = run; curn[j] = run; run += hist[j]; }
        rp[NPB] = run;
    }
    __syncthreads();
    const float ab = attn_b[0];
    for (int i = t; i < total; i += 256) {   // pass A: exp + denom accumulate
        unsigned e = raw[i];
        int dl = e & 31;
        int s = (int)(e >> 5);
        float sc = s_src[s] + sdl[dl] + ab;
        sc = sc >= 0.f ? sc : 0.01f * sc;   // leaky_relu; |sc| small, exp safe
        float w = expf(sc);
        int pos = atomicAdd(&curn[dl], 1);
        srt[pos] = ((unsigned)s << 16) | (unsigned)dl;
        wbuf[pos] = w;
        atomicAdd(&dsum[dl], w);
    }
    __syncthreads();
    if (t < NPB) dinv[t] = dsum[t] > 0.f ? 1.f / dsum[t] : 0.f;
    __syncthreads();
    for (int i = t; i < total; i += 256) {   // pass B: normalize + pack
        unsigned e = srt[i];
        float a = wbuf[i] * dinv[e & 31];
        gb[i] = (e & 0xFFFF0000u) | (unsigned)__half_as_ushort(__float2half(a));
    }
    if (t <= NPB) rp_g[bkt * 32 + t] = rp[t];
}

__device__ __forceinline__ void accum8(float4& A, float4& B, uint4 u, float w) {
    __half2 p0 = *(const __half2*)&u.x;
    __half2 p1 = *(const __half2*)&u.y;
    __half2 p2 = *(const __half2*)&u.z;
    __half2 p3 = *(const __half2*)&u.w;
    float2 f0 = __half22float2(p0), f1 = __half22float2(p1);
    float2 f2 = __half22float2(p2), f3 = __half22float2(p3);
    A.x = fmaf(w, f0.x, A.x); A.y = fmaf(w, f0.y, A.y);
    A.z = fmaf(w, f1.x, A.z); A.w = fmaf(w, f1.y, A.w);
    B.x = fmaf(w, f2.x, B.x); B.y = fmaf(w, f2.y, B.y);
    B.z = fmaf(w, f3.x, B.z); B.w = fmaf(w, f3.y, B.w);
}

__device__ __forceinline__ float wdec(unsigned e) {
    return __half2float(__ushort_as_half((unsigned short)(e & 0xFFFFu)));
}

// gather v3: LANE-PRIVATE accumulation - no cross-lane reduce at all.
// Block = (5 buckets, dim-quarter); 512 threads = 125 node-groups of 4 lanes
// (+3 idle). Each lane owns (node, 8 dims): serial edge loop, 4-deep unroll
// with predicated dummy edges (word 0 -> w=0, src 0, L1-hot). 16 node-groups
// advance per wave-inst; 4 loads in flight per LANE = 64+ per wave (16x the
// old 8-lane-group scheme whose 12-deep shfl chain + 4-deep MLP left waves
// ~90% latency-stalled). blk&7 still pins quarter->XCD (3.2 MB L2 slice).
__global__ __launch_bounds__(512) void k_gather(const __half* __restrict__ h16q,
                                                const unsigned* __restrict__ gep,
                                                const int* __restrict__ rp_g,
                                                float* __restrict__ out) {
    __shared__ unsigned se[NBG * CAP_LDS];   // 25.6 KB
    __shared__ int rp[NBG * 32];             // 640 B (26 used per bucket)
    const int blk = blockIdx.x;
    const int x = blk & 7;
    const int qq = x & 3;                            // dim quarter
    const int bg = ((blk >> 3) << 1) + (x >> 2);     // bucket-group 0..399
    const int bkt0 = bg * NBG;
    const int t = threadIdx.x;
    if (t < NBG * 32 && (t & 31) <= NPB)
        rp[t] = rp_g[(bkt0 + (t >> 5)) * 32 + (t & 31)];
    __syncthreads();
#pragma unroll
    for (int b = 0; b < NBG; b++) {
        const unsigned* gb = gep + (size_t)(bkt0 + b) * (NCH * CAPC);
        const int tot = rp[b * 32 + NPB];
        for (int i = t; i < tot; i += 512) se[b * CAP_LDS + i] = gb[i];
    }
    __syncthreads();
    const int g = t >> 2, dp = t & 3;   // node-group, 16B-slice within quarter
    if (g < NGRP) {
        const int b = g / NPB, n = g - b * NPB;      // magic-mul const div
        const int lo = rp[b * 32 + n], hi = rp[b * 32 + n + 1];
        const unsigned* seb = se + b * CAP_LDS;
        const uint4* hq = (const uint4*)h16q + (size_t)qq * (N_NODES * 4) + dp;
        float4 A = {0.f, 0.f, 0.f, 0.f}, B = {0.f, 0.f, 0.f, 0.f};
        for (int i = lo; i < hi; i += 4) {
            unsigned e0 = seb[i];
            unsigned e1 = (i + 1 < hi) ? seb[i + 1] : 0u;
            unsigned e2 = (i + 2 < hi) ? seb[i + 2] : 0u;
            unsigned e3 = (i + 3 < hi) ? seb[i + 3] : 0u;
            uint4 u0 = hq[(e0 >> 16) * 4];
            uint4 u1 = hq[(e1 >> 16) * 4];
            uint4 u2 = hq[(e2 >> 16) * 4];
            uint4 u3 = hq[(e3 >> 16) * 4];
            accum8(A, B, u0, wdec(e0));
            accum8(A, B, u1, wdec(e1));
            accum8(A, B, u2, wdec(e2));
            accum8(A, B, u3, wdec(e3));
        }
        // out row = (bkt0+b)*25 + n = bg*125 + g; lane's 8 dims contiguous
        float4* o = (float4*)(out + (size_t)(bg * 125 + g) * 128 + qq * 32 + dp * 8);
        o[0] = A;
        o[1] = B;
    }
}

extern "C" void kernel_launch(void* const* d_in, const int* in_sizes, int n_in,
                              void* d_out, int out_size, void* d_ws, size_t ws_size,
                              hipStream_t stream) {
    const float* feat   = (const float*)d_in[0];
    const int*   src    = (const int*)d_in[1];
    const int*   dst    = (const int*)d_in[2];
    const float* W      = (const float*)d_in[3];
    const float* b      = (const float*)d_in[4];
    const float* attn_w = (const float*)d_in[5];
    const float* attn_b = (const float*)d_in[6];
    const float* mask   = (const float*)d_in[7];
    float* out = (float*)d_out;

    char* ws = (char*)d_ws;
    __half*   h16q  = (__half*)(ws + 0);
    float*    s_src = (float*)(ws + 12800000);
    float*    s_dst = (float*)(ws + 13000000);
    int*      cnt   = (int*)(ws + 13200000);
    unsigned* gep   = (unsigned*)(ws + 14000000);
    int*      rp_g  = (int*)(ws + 39600000);
    __half*   w16q  = (__half*)(ws + 39856000);
    float*    waSD  = (float*)(ws + 39888768);
    float*    cst   = (float*)(ws + 39889792);

    k_prep<<<41, 256, 0, stream>>>(W, b, attn_w, w16q, waSD, cst);
    k_fusedA<<<PLACE_BLOCKS + PROJ_BLOCKS, 512, 0, stream>>>(
        feat, b, mask, src, dst, h16q, s_src, s_dst, cnt, gep, w16q, waSD, cst);
    k_sort<<<NB, 256, 0, stream>>>(s_src, s_dst, attn_b, cnt, gep, rp_g);
    k_gather<<<GQ_BLOCKS, 512, 0, stream>>>(h16q, gep, rp_g, out);
}